// Round 5
// baseline (102.611 us; speedup 1.0000x reference)
//
#include <hip/hip_runtime.h>

#define S_ROWS 2048
#define RO_ROWS 8192
#define HEADS 8
#define HDIM 32
#define ROWLEN 256           // HEADS * HDIM
#define NB_S (S_ROWS / 16)   // 128 fragment-blocks of s
#define NB_RO (RO_ROWS / 16) // 512 fragment-blocks of ro

typedef __attribute__((ext_vector_type(8))) short bf16x8;
typedef __attribute__((ext_vector_type(4))) float f32x4;
typedef __attribute__((ext_vector_type(4))) short s16x4;

__device__ __forceinline__ short f32_to_bf16_rne(float f) {
    union { float f; unsigned u; } v; v.f = f;
    return (short)((v.u + 0x7fffu + ((v.u >> 16) & 1u)) >> 16);
}

// Normalize every 32-elem head vector; emit bf16 fragment-major
// [H][N/16][16][32] (one 16x32 MFMA fragment = contiguous 1 KiB).
// Thread mapping puts (dg, r16) in the LOW bits so each wave's 64 stores are
// one contiguous 512B segment; reads are 8 x 128B full-line segments.
// Threads sharing a head vector differ only in dg = lane&7 -> shfl_xor 1/2/4.
__global__ __launch_bounds__(256) void mhd_normalize(const float* __restrict__ s,
                                                     const float* __restrict__ ro,
                                                     short* __restrict__ sF,
                                                     short* __restrict__ roF) {
    const int v   = blockIdx.x * 256 + threadIdx.x;  // vec4-element id
    const int dg  = v & 7;            // 4-elem group within head
    const int r16 = (v >> 3) & 15;    // row within fragment block
    const int u   = v >> 7;           // (h, nb) chunk id, 0..5119
    const int h   = u & 7;
    const int nb_all = u >> 3;        // 0..639
    const bool isS = nb_all < NB_S;
    const int nb  = isS ? nb_all : nb_all - NB_S;
    const int n   = nb * 16 + r16;    // source row within its tensor

    const float* src = isS ? s : ro;
    f32x4 x = *(const f32x4*)(src + (size_t)n * ROWLEN + h * HDIM + dg * 4);
    float ss = x[0] * x[0] + x[1] * x[1] + x[2] * x[2] + x[3] * x[3];
    ss += __shfl_xor(ss, 1);
    ss += __shfl_xor(ss, 2);
    ss += __shfl_xor(ss, 4);
    const float inv = rsqrtf(ss);
    s16x4 r;
    r[0] = f32_to_bf16_rne(x[0] * inv);
    r[1] = f32_to_bf16_rne(x[1] * inv);
    r[2] = f32_to_bf16_rne(x[2] * inv);
    r[3] = f32_to_bf16_rne(x[3] * inv);

    short* dst = isS ? sF : roF;
    const int NB = isS ? NB_S : NB_RO;
    *(s16x4*)(dst + ((size_t)(h * NB + nb) * 16 + r16) * 32 + dg * 4) = r;
}

// Wave tile 64x64; block = 4 waves (2x2) -> 128x128; grid 1024 (= 8 XCD x 128,
// bijective swizzle: each XCD owns a contiguous 8 MB output region).
// Structure: all 32 ro-fragments (B) stay register-resident (128 VGPR);
// outer loop over the 4 output row-chunks streams s-fragments (A) per head
// and STORES each 16x64 chunk as soon as its heads complete -> load and
// store streams overlap instead of a terminal 64 KB burst per wave.
// mfma(B, A): D lane-axis (lane&15) = s-row, reg-axis = 4 consecutive
// ro-cols. Epilogue repacks via wave-private padded LDS so each store instr
// covers 4 rows x 256B.
__global__ __launch_bounds__(256) void mhd_dist(const short* __restrict__ sF,
                                                const short* __restrict__ roF,
                                                float* __restrict__ out) {
    __shared__ float lds[4][16][68];  // 68 = 64 + 4 pad
    const int lane = threadIdx.x & 63;
    const int wave = threadIdx.x >> 6;
    const int wr = wave >> 1;
    const int wc = wave & 1;
    const int bid = blockIdx.x;
    const int swz = (bid & 7) * 128 + (bid >> 3);   // XCD-contiguous output
    const int tile_r = swz >> 6;      // 16 row tiles of 128
    const int tile_c = swz & 63;      // 64 col tiles of 128
    const int l15 = lane & 15;
    const int kg = lane >> 4;

    const int nbA = tile_r * 8 + wr * 4;   // first s fragment-block
    const int nbB = tile_c * 8 + wc * 4;   // first ro fragment-block
    const size_t laneOff = (size_t)l15 * 32 + kg * 8;

    // B resident: [h][j], all indices compile-time (fully unrolled)
    bf16x8 B[HEADS][4];
#pragma unroll
    for (int h = 0; h < HEADS; ++h)
#pragma unroll
        for (int j = 0; j < 4; ++j)
            B[h][j] = *(const bf16x8*)(roF + (size_t)(h * NB_RO + nbB + j) * 512 + laneOff);

    float* outBase = out + (size_t)(tile_r * 128 + wr * 64) * RO_ROWS
                         + tile_c * 128 + wc * 64;
    const int srow = lane >> 4;        // 0..3: row within a 4-row store group
    const int scol = (lane & 15) * 4;  // f32 col within the 64-wide tile

#pragma unroll
    for (int i = 0; i < 4; ++i) {
        f32x4 runmax[4];
#pragma unroll
        for (int j = 0; j < 4; ++j)
            runmax[j] = (f32x4){-3.0e38f, -3.0e38f, -3.0e38f, -3.0e38f};

#pragma unroll
        for (int h = 0; h < HEADS; ++h) {
            const bf16x8 a = *(const bf16x8*)(sF + (size_t)(h * NB_S + nbA + i) * 512 + laneOff);
#pragma unroll
            for (int j = 0; j < 4; ++j) {
                f32x4 acc = {0.f, 0.f, 0.f, 0.f};
                acc = __builtin_amdgcn_mfma_f32_16x16x32_bf16(B[h][j], a, acc, 0, 0, 0);
#pragma unroll
                for (int q = 0; q < 4; ++q)
                    runmax[j][q] = fmaxf(runmax[j][q], acc[q]);
            }
        }

        // repack chunk i through wave-private LDS, store 4 x (4 rows x 256B)
#pragma unroll
        for (int j = 0; j < 4; ++j)
            *(f32x4*)&lds[wave][l15][kg * 4 + j * 16] = runmax[j];
#pragma unroll
        for (int t = 0; t < 4; ++t) {
            const int rowL = t * 4 + srow;
            f32x4 vv = *(const f32x4*)&lds[wave][rowL][scol];
            *(f32x4*)(outBase + (size_t)(i * 16 + rowL) * RO_ROWS + scol) = vv;
        }
    }
}

extern "C" void kernel_launch(void* const* d_in, const int* in_sizes, int n_in,
                              void* d_out, int out_size, void* d_ws, size_t ws_size,
                              hipStream_t stream) {
    const float* batch_s  = (const float*)d_in[0];
    const float* batch_ro = (const float*)d_in[1];
    float* out = (float*)d_out;

    short* sF  = (short*)d_ws;                  // 2048*256 bf16 = 1 MiB
    short* roF = sF + (size_t)S_ROWS * ROWLEN;  // 8192*256 bf16 = 4 MiB

    const int totalV4 = (S_ROWS + RO_ROWS) * ROWLEN / 4;   // 655360 (exact x256)
    mhd_normalize<<<totalV4 / 256, 256, 0, stream>>>(batch_s, batch_ro, sF, roF);

    mhd_dist<<<(S_ROWS / 128) * (RO_ROWS / 128), 256, 0, stream>>>(sF, roF, out);
}